// Round 2
// baseline (75.205 us; speedup 1.0000x reference)
//
#include <hip/hip_runtime.h>
#include <hip/hip_bf16.h>

namespace {

constexpr int NSYM = 14;
constexpr int NSC  = 3072;
constexpr int NRB  = 256;   // NSC / 12
constexpr int NRr  = 2;     // rx antennas
constexpr int NTt  = 4;     // tx antennas
constexpr int NSs  = 2;     // streams
constexpr int NC   = 2048;  // codebook size

constexpr float N_VAR  = 0.1f;   // 1 / 10^(10/10)
constexpr float A_INFO = 0.83f;
constexpr float B_INFO = 0.73f;

struct c32 { float x, y; };

__device__ __forceinline__ c32 cmul(c32 a, c32 b) {
  return c32{a.x * b.x - a.y * b.y, a.x * b.y + a.y * b.x};
}
// a * conj(b)
__device__ __forceinline__ c32 cmulc(c32 a, c32 b) {
  return c32{a.x * b.x + a.y * b.y, a.y * b.x - a.x * b.y};
}
__device__ __forceinline__ c32 cadd(c32 a, c32 b) { return c32{a.x + b.x, a.y + b.y}; }
__device__ __forceinline__ c32 csub(c32 a, c32 b) { return c32{a.x - b.x, a.y - b.y}; }
__device__ __forceinline__ float cabs2(c32 a) { return a.x * a.x + a.y * a.y; }
__device__ __forceinline__ c32 cdiv(c32 a, c32 b) {
  float d = b.x * b.x + b.y * b.y;
  return c32{(a.x * b.x + a.y * b.y) / d, (a.y * b.x - a.x * b.y) / d};
}

// Mirrors the reference per-(candidate, rb) math in f32, same op order.
__device__ float rate_for(const c32 H[NRr][NTt], const c32 W[NTt][NSs]) {
  // h_eff[n][s] = sum_t H[n][t] * W[t][s]
  c32 he[NRr][NSs];
  for (int n = 0; n < NRr; ++n)
    for (int s = 0; s < NSs; ++s) {
      c32 acc{0.f, 0.f};
      for (int t = 0; t < NTt; ++t) acc = cadd(acc, cmul(H[n][t], W[t][s]));
      he[n][s] = acc;
    }

  // A = h_eff @ h_eff^H + n_var I
  c32 A00{0.f,0.f}, A01{0.f,0.f}, A10{0.f,0.f}, A11{0.f,0.f};
  for (int s = 0; s < NSs; ++s) {
    A00 = cadd(A00, cmulc(he[0][s], he[0][s]));
    A01 = cadd(A01, cmulc(he[0][s], he[1][s]));
    A10 = cadd(A10, cmulc(he[1][s], he[0][s]));
    A11 = cadd(A11, cmulc(he[1][s], he[1][s]));
  }
  A00.x += N_VAR;
  A11.x += N_VAR;

  // 2x2 complex inverse (adjugate / det)
  c32 det = csub(cmul(A00, A11), cmul(A01, A10));
  c32 Ainv[2][2];
  Ainv[0][0] = cdiv(A11, det);
  Ainv[0][1] = cdiv(c32{-A01.x, -A01.y}, det);
  Ainv[1][0] = cdiv(c32{-A10.x, -A10.y}, det);
  Ainv[1][1] = cdiv(A00, det);

  // G[s][n] = sum_m conj(he[m][s]) * Ainv[m][n]
  c32 G[NSs][NRr];
  for (int s = 0; s < NSs; ++s)
    for (int n = 0; n < NRr; ++n) {
      c32 acc{0.f, 0.f};
      for (int m = 0; m < NRr; ++m) {
        c32 hc{he[m][s].x, -he[m][s].y};
        acc = cadd(acc, cmul(hc, Ainv[m][n]));
      }
      G[s][n] = acc;
    }

  // T = G @ h_eff ; per-stream SINR ; rate
  float rate = 0.f;
  for (int s = 0; s < NSs; ++s) {
    float tot = 0.f, sig = 0.f;
    for (int p = 0; p < NSs; ++p) {
      c32 acc{0.f, 0.f};
      for (int n = 0; n < NRr; ++n) acc = cadd(acc, cmul(G[s][n], he[n][p]));
      float a2 = cabs2(acc);
      tot += a2;
      if (p == s) sig = a2;
    }
    float gsum = 0.f;
    for (int n = 0; n < NRr; ++n) gsum += cabs2(G[s][n]);
    float noise  = N_VAR * gsum;
    float interf = tot - sig;
    float sinr   = sig / (interf + noise);
    // EESM over a singleton axis with beta=0.25 is exactly identity here.
    rate += A_INFO * log2f(1.0f + B_INFO * sinr);
  }
  return rate;
}

__global__ __launch_bounds__(256)
void csi_pmi_kernel(const float* __restrict__ hr, const float* __restrict__ hi,
                    const float* __restrict__ cr, const float* __restrict__ ci,
                    float* __restrict__ out, int prec_per_rb) {
  const int rb  = blockIdx.x;
  const int tid = threadIdx.x;

  // ---- Stage 1: per-RB channel H (mean over 14 syms, then mean over 12 SCs) ----
  __shared__ float sP[8][12][2];  // raw per-(rt, sc-in-rb) sums over symbols
  __shared__ float sH[8][2];      // final H per (r*4+t)

  if (tid < 96) {
    const int rt = tid / 12;      // r*4 + t
    const int q  = tid % 12;
    const int base = rt * (NSYM * NSC) + rb * 12 + q;
    float sr = 0.f, si = 0.f;
    #pragma unroll
    for (int sym = 0; sym < NSYM; ++sym) {
      sr += hr[base + sym * NSC];
      si += hi[base + sym * NSC];
    }
    sP[rt][q][0] = sr;
    sP[rt][q][1] = si;
  }
  __syncthreads();
  if (tid < 8) {
    float ar = 0.f, ai = 0.f;
    #pragma unroll
    for (int q = 0; q < 12; ++q) {
      ar += sP[tid][q][0] / 14.0f;   // mean over syms first (ref order)
      ai += sP[tid][q][1] / 14.0f;
    }
    sH[tid][0] = ar / 12.0f;          // then mean over the 12 SCs
    sH[tid][1] = ai / 12.0f;
  }
  __syncthreads();

  c32 H[NRr][NTt];
  for (int r = 0; r < NRr; ++r)
    for (int t = 0; t < NTt; ++t)
      H[r][t] = c32{sH[r * 4 + t][0], sH[r * 4 + t][1]};

  // ---- Stage 2: evaluate 2048 candidates, 8 per thread (strided) ----
  float best = -INFINITY;
  int   bidx = 0;
  for (int k = 0; k < NC / 256; ++k) {
    const int c = k * 256 + tid;
    const float* crp = cr + c * 8;
    const float* cip = ci + c * 8;
    float re[8], im[8], n2 = 0.f;
    #pragma unroll
    for (int j = 0; j < 8; ++j) {
      re[j] = crp[j];
      im[j] = cip[j];
      n2 += re[j] * re[j] + im[j] * im[j];
    }
    const float nrm = sqrtf(n2);     // Frobenius norm (ref: sqrt(sum |w|^2))
    c32 W[NTt][NSs];
    #pragma unroll
    for (int t = 0; t < NTt; ++t)
      #pragma unroll
      for (int s = 0; s < NSs; ++s) {
        const int j = t * NSs + s;
        W[t][s] = c32{re[j] / nrm, im[j] / nrm};  // ref divides, mirror it
      }
    const float rate = rate_for(H, W);
    if (rate > best) { best = rate; bidx = c; }  // strictly >, keeps first (c increasing)
  }

  // ---- Stage 3: block argmax with first-index tie-break ----
  __shared__ float s_r[256];
  __shared__ int   s_i[256];
  s_r[tid] = best;
  s_i[tid] = bidx;
  __syncthreads();
  for (int off = 128; off > 0; off >>= 1) {
    if (tid < off) {
      const float r2 = s_r[tid + off];
      const int   i2 = s_i[tid + off];
      const float r1 = s_r[tid];
      const int   i1 = s_i[tid];
      if (r2 > r1 || (r2 == r1 && i2 < i1)) { s_r[tid] = r2; s_i[tid] = i2; }
    }
    __syncthreads();
  }

  const int   bestc = s_i[0];
  const float bestr = s_r[0];
  if (tid == 0) {
    out[rb]       = (float)bestc;   // PMI
    out[NRB + rb] = bestr;          // selected rate
  }

  // ---- Stage 4: write W[PMI] (normalized), re/im interleaved, row-major [4][2] ----
  if (prec_per_rb == 16) {
    if (tid < 16) {
      float n2b = 0.f;
      #pragma unroll
      for (int u = 0; u < 8; ++u) {
        const float a = cr[bestc * 8 + u];
        const float b = ci[bestc * 8 + u];
        n2b += a * a + b * b;
      }
      const float nrm = sqrtf(n2b);
      const int j = tid >> 1;
      const float v = ((tid & 1) ? ci[bestc * 8 + j] : cr[bestc * 8 + j]) / nrm;
      out[2 * NRB + rb * 16 + tid] = v;
    }
  } else if (prec_per_rb == 8) {   // fallback: real parts only
    if (tid < 8) {
      float n2b = 0.f;
      #pragma unroll
      for (int u = 0; u < 8; ++u) {
        const float a = cr[bestc * 8 + u];
        const float b = ci[bestc * 8 + u];
        n2b += a * a + b * b;
      }
      const float nrm = sqrtf(n2b);
      out[2 * NRB + rb * 8 + tid] = cr[bestc * 8 + tid] / nrm;
    }
  }
}

}  // namespace

extern "C" void kernel_launch(void* const* d_in, const int* in_sizes, int n_in,
                              void* d_out, int out_size, void* d_ws, size_t ws_size,
                              hipStream_t stream) {
  const float* hr = (const float*)d_in[0];
  const float* hi = (const float*)d_in[1];
  const float* cr = (const float*)d_in[2];
  const float* ci = (const float*)d_in[3];
  float* out = (float*)d_out;

  int prec_per_rb = (out_size - 2 * NRB) / NRB;  // 16 (re/im interleaved) or 8 (real only)
  if (prec_per_rb != 8 && prec_per_rb != 16) prec_per_rb = 16;

  csi_pmi_kernel<<<NRB, 256, 0, stream>>>(hr, hi, cr, ci, out, prec_per_rb);
}